// Round 5
// baseline (421.167 us; speedup 1.0000x reference)
//
#include <hip/hip_runtime.h>
#include <hip/hip_fp16.h>
#include <cstddef>

#define Bc   32
#define Nc   512
#define Mc   512
#define DFc  64
#define BIGC 1.0e10f
#define LOG2E_F 1.4426950408889634f
#define LN2_F   0.6931471805599453f

typedef unsigned int uint32;

// lane l gets lane l-1's src; lane 0 gets `oldv`  (DPP wave_shr:1)
__device__ __forceinline__ float dpp_shr1(float oldv, float src) {
    return __int_as_float(__builtin_amdgcn_update_dpp(
        __float_as_int(oldv), __float_as_int(src), 0x138, 0xf, 0xf, false));
}
// shift with don't-care lane0 (single v_mov_b32_dpp, no old-copy)
__device__ __forceinline__ float dpp_shr1_nc(float src) {
    return __int_as_float(__builtin_amdgcn_mov_dpp(
        __float_as_int(src), 0x138, 0xf, 0xf, false));
}
// softmin in log2 domain; min term's exp2 is exactly 1 -> only 2 trans+log
__device__ __forceinline__ float softmin3(float a, float b, float c) {
    float mn = fminf(fminf(a, b), c);          // v_min3
    float mx = fmaxf(fmaxf(a, b), c);          // v_max3
    float md = __builtin_amdgcn_fmed3f(a, b, c);
    float e  = 1.0f + exp2f(mn - mx) + exp2f(mn - md);
    return mn - log2f(e);
}

// ---------------------------------------------------------------------------
// Kernel 1 (unchanged from r4): distances in SCALED (x LOG2E) fp16, packed:
//   tile = (b*4 + strip)*8 + J; uint4 [gi*64+l], component e (pair p=4gi+e):
//     half2( D[128*strip + 2l][64J + c], D[128*strip + 2l + 1][64J + c] )*LOG2E
//   with c = 4*gi + e - l (clamped garbage outside [0,64) — never consumed).
// ---------------------------------------------------------------------------
__global__ __launch_bounds__(256) void dist_kernel(
    const float* __restrict__ X, const float* __restrict__ Y,
    uint32* __restrict__ Dsk)
{
    __shared__ __align__(16) float Xs[128][68];
    __shared__ __align__(16) float Ys[64][68];

    const int b  = blockIdx.z;
    const int n0 = blockIdx.y * 128;
    const int m0 = blockIdx.x * 64;
    const int tid = threadIdx.x;

    const float* Xg = X + ((size_t)b * Nc + n0) * DFc;
    const float* Yg = Y + ((size_t)b * Mc + m0) * DFc;

#pragma unroll
    for (int it = 0; it < 8; ++it) {
        int e4 = it * 256 + tid;
        int n = e4 >> 4, k = (e4 & 15) * 4;
        *(float4*)&Xs[n][(k + 4 * n) & 63] = *(const float4*)&Xg[e4 * 4];
    }
#pragma unroll
    for (int it = 0; it < 4; ++it) {
        int e4 = it * 256 + tid;
        int n = e4 >> 4, k = (e4 & 15) * 4;
        *(float4*)&Ys[n][k] = *(const float4*)&Yg[e4 * 4];
    }
    __syncthreads();

    const int tx = tid & 15;
    const int ty = tid >> 4;

    float acc[8][4];
#pragma unroll
    for (int a = 0; a < 8; ++a)
#pragma unroll
        for (int c = 0; c < 4; ++c) acc[a][c] = 0.0f;

#pragma unroll
    for (int k4 = 0; k4 < 16; ++k4) {
        float4 xv[8], yv[4];
#pragma unroll
        for (int a = 0; a < 8; ++a) {
            int r = ty + 16 * a;
            xv[a] = *(const float4*)&Xs[r][(k4 * 4 + 4 * r) & 63];
        }
#pragma unroll
        for (int c = 0; c < 4; ++c)
            yv[c] = *(const float4*)&Ys[tx + 16 * c][k4 * 4];
#pragma unroll
        for (int a = 0; a < 8; ++a) {
#pragma unroll
            for (int c = 0; c < 4; ++c) {
                float d0 = xv[a].x - yv[c].x;
                float d1 = xv[a].y - yv[c].y;
                float d2 = xv[a].z - yv[c].z;
                float d3 = xv[a].w - yv[c].w;
                acc[a][c] = fmaf(d0, d0,
                            fmaf(d1, d1,
                            fmaf(d2, d2,
                            fmaf(d3, d3, acc[a][c]))));
            }
        }
    }
    __syncthreads();

    float* Ct = (float*)Xs;
#pragma unroll
    for (int a = 0; a < 8; ++a) {
        int r = ty + 16 * a;
#pragma unroll
        for (int c = 0; c < 4; ++c)
            Ct[r * 66 + tx + 16 * c] = acc[a][c];
    }
    __syncthreads();

    const int l = tid & 63;
    const int q = tid >> 6;
    uint4* outt = (uint4*)Dsk +
        (((size_t)b * 4 + blockIdx.y) * 8 + blockIdx.x) * 2048;
    const float* CrowA = Ct + (2 * l) * 66;
    const float* CrowB = Ct + (2 * l + 1) * 66;
#pragma unroll
    for (int g = 0; g < 8; ++g) {
        int gi = q + 4 * g;
        uint32 u[4];
#pragma unroll
        for (int e = 0; e < 4; ++e) {
            int c = min(max(4 * gi + e - l, 0), 63);
            __half2 h = __floats2half2_rn(CrowA[c] * LOG2E_F,
                                          CrowB[c] * LOG2E_F);
            u[e] = *(uint32*)&h;
        }
        uint4 v; v.x = u[0]; v.y = u[1]; v.z = u[2]; v.w = u[3];
        outt[gi * 64 + l] = v;
    }
}

// ---------------------------------------------------------------------------
// Kernel 2: tile-systolic scan, 2 rows/lane, TWO batches per block:
// waves 0-3 -> batch 2*blk, waves 4-7 -> batch 2*blk+1  (2 chains per SIMD
// fill each other's dependency stalls). Per batch-group identical r4 math.
// Phase-split tile: s=1..64 inject-only (no stores), s=65..128 store-only
// (no inject). 4-deep slot-reuse dwordx4 D prefetch. softmin via med3
// (2 exp2 + 1 log2). Hold-semantics registers carry state across tiles.
// ---------------------------------------------------------------------------
__global__ __launch_bounds__(512) void scan_kernel(
    const uint32* __restrict__ Dsk,
    const int* __restrict__ X_len, const int* __restrict__ Y_len,
    float* __restrict__ out)
{
    __shared__ __align__(16) float Frow[8][516];
    __shared__ float dumpArr[80];

    const int tid = threadIdx.x;
    const int l  = tid & 63;
    const int wu = __builtin_amdgcn_readfirstlane(tid >> 6);  // 0..7
    const int wl = wu & 3;              // strip within batch
    const int g  = wu >> 2;             // batch slot in block
    const int bb = blockIdx.x * 2 + g;

    const int xl = X_len[bb], yl = Y_len[bb];
    const int wxl = (xl - 1) >> 7;            // capture strip
    const int iw  = (xl - 1) & 127;
    const int lcap = iw >> 1;                 // capture lane
    const int useB = iw & 1;                  // row parity within lane
    const int Jcap = (yl - 1) >> 6;           // capture tile
    const int scapBase = (yl - (Jcap << 6)) + lcap;   // in [1,127]

    const bool is63 = (l == 63);

    if (l == 0) Frow[wu][0] = BIGC;   // col-0 border, read as f0 at J=0
    __syncthreads();

    float curA = BIGC, curB = BIGC;
    float diagA = (wl == 0 && l == 0) ? 0.0f : BIGC;
    float capv = 0.0f;

    for (int k = 0; k < 11; ++k) {
        int J = k - wl;
        if (0 <= J && J < 8) {
            const int j0 = J << 6;
            float Fv, f0;
            if (wl > 0) {
                Fv = Frow[wu - 1][j0 + 1 + l];   // frontier cols j0+1..j0+64
                f0 = Frow[wu - 1][j0];           // frontier col j0 (diag seed)
            } else {
                Fv = BIGC;
                f0 = (J == 0) ? 0.0f : BIGC;     // R[0][0]=0, else border
            }
            // lane0's diag for its first step of this tile = frontier col j0
            diagA = (l == 0) ? f0 : diagA;

            const uint4* tp = (const uint4*)Dsk +
                ((((size_t)bb * 4 + wl) * 8) + J) * 2048 + l;
            const int scap = (wl == wxl && J == Jcap) ? scapBase : -1000;
            float* wb = is63 ? (&Frow[wu][0] + j0 + 1) : dumpArr;

            uint4 dreg[4];
            dreg[0] = tp[0];   dreg[1] = tp[64];
            dreg[2] = tp[128]; dreg[3] = tp[192];

            // ---- phase 1: gi 0..15, s = 1..64: lane0 inject, no stores ----
#pragma unroll 1
            for (int m = 0; m < 4; ++m) {
#pragma unroll
                for (int q = 0; q < 4; ++q) {
                    const int gi = m * 4 + q;            // gi & 3 == q
                    uint4 dc = dreg[q];
                    dreg[q] = tp[(gi + 4) * 64];         // 4-deep slot reuse
                    const uint32 du[4] = {dc.x, dc.y, dc.z, dc.w};
#pragma unroll
                    for (int e = 0; e < 4; ++e) {
                        const int s = 4 * gi + e + 1;    // 1..64
                        float2 d2 = __half22float2(*(const __half2*)&du[e]);
                        float fs = __int_as_float(__builtin_amdgcn_readlane(
                            __float_as_int(Fv), s - 1));
                        float upA = dpp_shr1(fs, curB);
                        float valA = softmin3(diagA, upA, curA) + d2.x;
                        float valB = softmin3(curA, valA, curB) + d2.y;
                        float vsel = useB ? valB : valA;
                        capv = (s == scap) ? vsel : capv;
                        bool act = (l <= s - 1);         // upper bound free here
                        curA = act ? valA : curA;
                        curB = act ? valB : curB;
                        diagA = upA;
                    }
                }
            }
            // s=64 frontier publish: lane63's curB (=valB@64) -> col j0+1
            wb[0] = curB;

            // ---- phase 2: gi 16..27, s = 65..112: no inject, store each ----
#pragma unroll 1
            for (int m = 4; m < 7; ++m) {
#pragma unroll
                for (int q = 0; q < 4; ++q) {
                    const int gi = m * 4 + q;
                    uint4 dc = dreg[q];
                    dreg[q] = tp[(gi + 4) * 64];
                    const uint32 du[4] = {dc.x, dc.y, dc.z, dc.w};
#pragma unroll
                    for (int e = 0; e < 4; ++e) {
                        const int s = 4 * gi + e + 1;    // 65..112
                        float2 d2 = __half22float2(*(const __half2*)&du[e]);
                        float upA = dpp_shr1_nc(curB);   // lane0 dead
                        float valA = softmin3(diagA, upA, curA) + d2.x;
                        float valB = softmin3(curA, valA, curB) + d2.y;
                        float vsel = useB ? valB : valA;
                        capv = (s == scap) ? vsel : capv;
                        bool act = (l >= s - 64);        // lower bound free here
                        curA = act ? valA : curA;
                        curB = act ? valB : curB;
                        diagA = upA;
                        wb[s - 64] = valB;               // imm-offset ds_write
                    }
                }
            }
            // ---- peel: gi 28..31, s = 113..128 (no prefetch; skip s=128) ----
#pragma unroll
            for (int q = 0; q < 4; ++q) {
                const int gi = 28 + q;
                uint4 dc = dreg[q];
                const uint32 du[4] = {dc.x, dc.y, dc.z, dc.w};
#pragma unroll
                for (int e = 0; e < 4; ++e) {
                    const int s = 4 * gi + e + 1;        // 113..128
                    float2 d2 = __half22float2(*(const __half2*)&du[e]);
                    float upA = dpp_shr1_nc(curB);
                    float valA = softmin3(diagA, upA, curA) + d2.x;
                    float valB = softmin3(curA, valA, curB) + d2.y;
                    float vsel = useB ? valB : valA;
                    capv = (s == scap) ? vsel : capv;
                    bool act = (l >= s - 64);
                    curA = act ? valA : curA;
                    curB = act ? valB : curB;
                    diagA = upA;
                    if (s != 128) wb[s - 64] = valB;
                }
            }
        }
        __syncthreads();
    }

    if (wl == wxl) {
        float o = __int_as_float(
            __builtin_amdgcn_readlane(__float_as_int(capv), lcap));
        if (l == 0) out[bb] = o * LN2_F;
    }
}

extern "C" void kernel_launch(void* const* d_in, const int* in_sizes, int n_in,
                              void* d_out, int out_size, void* d_ws, size_t ws_size,
                              hipStream_t stream)
{
    const float* X  = (const float*)d_in[0];
    const float* Y  = (const float*)d_in[1];
    const int*   xl = (const int*)d_in[2];
    const int*   yl = (const int*)d_in[3];
    float* out = (float*)d_out;
    uint32* Dsk = (uint32*)d_ws;   // 32 b * 4 strips * 8 J * 32 KB = 32 MB

    dist_kernel<<<dim3(8, 4, Bc), 256, 0, stream>>>(X, Y, Dsk);
    scan_kernel<<<Bc / 2, 512, 0, stream>>>(Dsk, xl, yl, out);
}

// Round 6
// 226.561 us; speedup vs baseline: 1.8590x; 1.8590x over previous
//
#include <hip/hip_runtime.h>
#include <hip/hip_fp16.h>
#include <cstddef>

#define Bc   32
#define Nc   512
#define Mc   512
#define DFc  64
#define BIGC 1.0e10f
#define LOG2E_F 1.4426950408889634f
#define LN2_F   0.6931471805599453f

typedef unsigned int uint32;

// lane l gets lane l-1's src; lane 0 gets `oldv`  (DPP wave_shr:1)
__device__ __forceinline__ float dpp_shr1(float oldv, float src) {
    return __int_as_float(__builtin_amdgcn_update_dpp(
        __float_as_int(oldv), __float_as_int(src), 0x138, 0xf, 0xf, false));
}
// shift with don't-care lane0 (single v_mov_b32_dpp)
__device__ __forceinline__ float dpp_shr1_nc(float src) {
    return __int_as_float(__builtin_amdgcn_mov_dpp(
        __float_as_int(src), 0x138, 0xf, 0xf, false));
}

// Scaled-domain softmin with BIT-TRICK exp2/log2 (no trans ops — v_exp/v_log
// are quarter-rate and dominated both issue and the dependent chain).
//   exp2(t), t<=0:  asfloat(u32(t*2^23 + 127*2^23)); u32 cvt saturates
//                   negatives to 0 == exact underflow for t < -126.
//   log2(E), E in [1,3]: f32(bits(E)) * 2^-23 - 127.
// Max per-softmin error ~0.09 (chord biases partially cancel); accumulated
// path error ~100-200 scaled, far under the 1259 absmax threshold.
__device__ __forceinline__ float softmin3f(float a, float b, float c) {
    float mn = fminf(fminf(a, b), c);
    float mx = fmaxf(fmaxf(a, b), c);
    float md = __builtin_amdgcn_fmed3f(a, b, c);
    float t1 = mn - mx;                       // <= 0
    float t2 = mn - md;                       // <= 0
    uint32 b1 = (uint32)fmaxf(fmaf(t1, 8388608.0f, 1065353216.0f), 0.0f);
    uint32 b2 = (uint32)fmaxf(fmaf(t2, 8388608.0f, 1065353216.0f), 0.0f);
    float E = 1.0f + (__int_as_float(b1) + __int_as_float(b2));
    float lg = fmaf((float)__float_as_uint(E), 1.1920929e-7f, -127.0f);
    return mn - lg;
}

// ---------------------------------------------------------------------------
// Kernel 1 (unchanged): distances in SCALED (x LOG2E) fp16, packed:
//   tile = (b*4 + strip)*8 + J; uint4 [gi*64+l], component e (pair p=4gi+e):
//     half2( D[128*strip + 2l][64J + c], D[128*strip + 2l + 1][64J + c] )*LOG2E
//   with c = 4*gi + e - l (clamped garbage outside [0,64) — never consumed).
// ---------------------------------------------------------------------------
__global__ __launch_bounds__(256) void dist_kernel(
    const float* __restrict__ X, const float* __restrict__ Y,
    uint32* __restrict__ Dsk)
{
    __shared__ __align__(16) float Xs[128][68];
    __shared__ __align__(16) float Ys[64][68];

    const int b  = blockIdx.z;
    const int n0 = blockIdx.y * 128;
    const int m0 = blockIdx.x * 64;
    const int tid = threadIdx.x;

    const float* Xg = X + ((size_t)b * Nc + n0) * DFc;
    const float* Yg = Y + ((size_t)b * Mc + m0) * DFc;

#pragma unroll
    for (int it = 0; it < 8; ++it) {
        int e4 = it * 256 + tid;
        int n = e4 >> 4, k = (e4 & 15) * 4;
        *(float4*)&Xs[n][(k + 4 * n) & 63] = *(const float4*)&Xg[e4 * 4];
    }
#pragma unroll
    for (int it = 0; it < 4; ++it) {
        int e4 = it * 256 + tid;
        int n = e4 >> 4, k = (e4 & 15) * 4;
        *(float4*)&Ys[n][k] = *(const float4*)&Yg[e4 * 4];
    }
    __syncthreads();

    const int tx = tid & 15;
    const int ty = tid >> 4;

    float acc[8][4];
#pragma unroll
    for (int a = 0; a < 8; ++a)
#pragma unroll
        for (int c = 0; c < 4; ++c) acc[a][c] = 0.0f;

#pragma unroll
    for (int k4 = 0; k4 < 16; ++k4) {
        float4 xv[8], yv[4];
#pragma unroll
        for (int a = 0; a < 8; ++a) {
            int r = ty + 16 * a;
            xv[a] = *(const float4*)&Xs[r][(k4 * 4 + 4 * r) & 63];
        }
#pragma unroll
        for (int c = 0; c < 4; ++c)
            yv[c] = *(const float4*)&Ys[tx + 16 * c][k4 * 4];
#pragma unroll
        for (int a = 0; a < 8; ++a) {
#pragma unroll
            for (int c = 0; c < 4; ++c) {
                float d0 = xv[a].x - yv[c].x;
                float d1 = xv[a].y - yv[c].y;
                float d2 = xv[a].z - yv[c].z;
                float d3 = xv[a].w - yv[c].w;
                acc[a][c] = fmaf(d0, d0,
                            fmaf(d1, d1,
                            fmaf(d2, d2,
                            fmaf(d3, d3, acc[a][c]))));
            }
        }
    }
    __syncthreads();

    float* Ct = (float*)Xs;
#pragma unroll
    for (int a = 0; a < 8; ++a) {
        int r = ty + 16 * a;
#pragma unroll
        for (int c = 0; c < 4; ++c)
            Ct[r * 66 + tx + 16 * c] = acc[a][c];
    }
    __syncthreads();

    const int l = tid & 63;
    const int q = tid >> 6;
    uint4* outt = (uint4*)Dsk +
        (((size_t)b * 4 + blockIdx.y) * 8 + blockIdx.x) * 2048;
    const float* CrowA = Ct + (2 * l) * 66;
    const float* CrowB = Ct + (2 * l + 1) * 66;
#pragma unroll
    for (int g = 0; g < 8; ++g) {
        int gi = q + 4 * g;
        uint32 u[4];
#pragma unroll
        for (int e = 0; e < 4; ++e) {
            int c = min(max(4 * gi + e - l, 0), 63);
            __half2 h = __floats2half2_rn(CrowA[c] * LOG2E_F,
                                          CrowB[c] * LOG2E_F);
            u[e] = *(uint32*)&h;
        }
        uint4 v; v.x = u[0]; v.y = u[1]; v.z = u[2]; v.w = u[3];
        outt[gi * 64 + l] = v;
    }
}

// ---------------------------------------------------------------------------
// Kernel 2: tile-systolic scan, 2 rows/lane, ONE batch per block (32 blocks
// x 256 threads = 4 waves, 1 wave/SIMD — r5's 2-batch co-location was
// issue-bound and halved CUs; reverted). Bit-trick softmin (no trans ops).
// Dead-tile skip: strips > wxl and tiles J > Jcap never touch the output;
// loop runs to kmax = wxl + Jcap (uniform per block).
// ---------------------------------------------------------------------------
__global__ __launch_bounds__(256) void scan_kernel(
    const uint32* __restrict__ Dsk,
    const int* __restrict__ X_len, const int* __restrict__ Y_len,
    float* __restrict__ out)
{
    __shared__ __align__(16) float Frow[4][516];
    __shared__ float dumpArr[80];

    const int tid = threadIdx.x;
    const int l  = tid & 63;
    const int wl = __builtin_amdgcn_readfirstlane(tid >> 6);  // strip 0..3
    const int bb = blockIdx.x;

    const int xl = X_len[bb], yl = Y_len[bb];
    const int wxl = (xl - 1) >> 7;            // capture strip
    const int iw  = (xl - 1) & 127;
    const int lcap = iw >> 1;                 // capture lane
    const int useB = iw & 1;                  // row parity within lane
    const int Jcap = (yl - 1) >> 6;           // capture tile
    const int scapBase = (yl - (Jcap << 6)) + lcap;   // in [1,127]
    const int kmax = wxl + Jcap;              // <= 10

    const bool is63 = (l == 63);

    if (l == 0) Frow[wl][0] = BIGC;   // col-0 border, read as f0 at J=0
    __syncthreads();

    float curA = BIGC, curB = BIGC;
    float diagA = (wl == 0 && l == 0) ? 0.0f : BIGC;
    float capv = 0.0f;

    for (int k = 0; k <= kmax; ++k) {
        int J = k - wl;
        if (wl <= wxl && 0 <= J && J <= Jcap) {
            const int j0 = J << 6;
            float Fv, f0;
            if (wl > 0) {
                Fv = Frow[wl - 1][j0 + 1 + l];   // frontier cols j0+1..j0+64
                f0 = Frow[wl - 1][j0];           // frontier col j0 (diag seed)
            } else {
                Fv = BIGC;
                f0 = (J == 0) ? 0.0f : BIGC;     // R[0][0]=0, else border
            }
            diagA = (l == 0) ? f0 : diagA;

            const uint4* tp = (const uint4*)Dsk +
                ((((size_t)bb * 4 + wl) * 8) + J) * 2048 + l;
            const int scap = (wl == wxl && J == Jcap) ? scapBase : -1000;
            float* wb = is63 ? (&Frow[wl][0] + j0 + 1) : dumpArr;

            uint4 dreg[4];
            dreg[0] = tp[0];   dreg[1] = tp[64];
            dreg[2] = tp[128]; dreg[3] = tp[192];

            // ---- phase 1: gi 0..15, s = 1..64: lane0 inject, no stores ----
#pragma unroll 1
            for (int m = 0; m < 4; ++m) {
#pragma unroll
                for (int q = 0; q < 4; ++q) {
                    const int gi = m * 4 + q;            // gi & 3 == q
                    uint4 dc = dreg[q];
                    dreg[q] = tp[(gi + 4) * 64];         // 4-deep slot reuse
                    const uint32 du[4] = {dc.x, dc.y, dc.z, dc.w};
#pragma unroll
                    for (int e = 0; e < 4; ++e) {
                        const int s = 4 * gi + e + 1;    // 1..64
                        float2 d2 = __half22float2(*(const __half2*)&du[e]);
                        float fs = __int_as_float(__builtin_amdgcn_readlane(
                            __float_as_int(Fv), s - 1));
                        float upA = dpp_shr1(fs, curB);
                        float valA = softmin3f(diagA, upA, curA) + d2.x;
                        float valB = softmin3f(curA, valA, curB) + d2.y;
                        float vsel = useB ? valB : valA;
                        capv = (s == scap) ? vsel : capv;
                        bool act = (l <= s - 1);
                        curA = act ? valA : curA;
                        curB = act ? valB : curB;
                        diagA = upA;
                    }
                }
            }
            // s=64 frontier publish: lane63's curB -> col j0+1
            wb[0] = curB;

            // ---- phase 2: gi 16..27, s = 65..112: no inject, store each ----
#pragma unroll 1
            for (int m = 4; m < 7; ++m) {
#pragma unroll
                for (int q = 0; q < 4; ++q) {
                    const int gi = m * 4 + q;
                    uint4 dc = dreg[q];
                    dreg[q] = tp[(gi + 4) * 64];
                    const uint32 du[4] = {dc.x, dc.y, dc.z, dc.w};
#pragma unroll
                    for (int e = 0; e < 4; ++e) {
                        const int s = 4 * gi + e + 1;    // 65..112
                        float2 d2 = __half22float2(*(const __half2*)&du[e]);
                        float upA = dpp_shr1_nc(curB);   // lane0 dead
                        float valA = softmin3f(diagA, upA, curA) + d2.x;
                        float valB = softmin3f(curA, valA, curB) + d2.y;
                        float vsel = useB ? valB : valA;
                        capv = (s == scap) ? vsel : capv;
                        bool act = (l >= s - 64);
                        curA = act ? valA : curA;
                        curB = act ? valB : curB;
                        diagA = upA;
                        wb[s - 64] = valB;               // imm-offset ds_write
                    }
                }
            }
            // ---- peel: gi 28..31, s = 113..128 (no prefetch; skip s=128) ----
#pragma unroll
            for (int q = 0; q < 4; ++q) {
                const int gi = 28 + q;
                uint4 dc = dreg[q];
                const uint32 du[4] = {dc.x, dc.y, dc.z, dc.w};
#pragma unroll
                for (int e = 0; e < 4; ++e) {
                    const int s = 4 * gi + e + 1;        // 113..128
                    float2 d2 = __half22float2(*(const __half2*)&du[e]);
                    float upA = dpp_shr1_nc(curB);
                    float valA = softmin3f(diagA, upA, curA) + d2.x;
                    float valB = softmin3f(curA, valA, curB) + d2.y;
                    float vsel = useB ? valB : valA;
                    capv = (s == scap) ? vsel : capv;
                    bool act = (l >= s - 64);
                    curA = act ? valA : curA;
                    curB = act ? valB : curB;
                    diagA = upA;
                    if (s != 128) wb[s - 64] = valB;
                }
            }
        }
        __syncthreads();
    }

    if (wl == wxl) {
        float o = __int_as_float(
            __builtin_amdgcn_readlane(__float_as_int(capv), lcap));
        if (l == 0) out[bb] = o * LN2_F;
    }
}

extern "C" void kernel_launch(void* const* d_in, const int* in_sizes, int n_in,
                              void* d_out, int out_size, void* d_ws, size_t ws_size,
                              hipStream_t stream)
{
    const float* X  = (const float*)d_in[0];
    const float* Y  = (const float*)d_in[1];
    const int*   xl = (const int*)d_in[2];
    const int*   yl = (const int*)d_in[3];
    float* out = (float*)d_out;
    uint32* Dsk = (uint32*)d_ws;   // 32 b * 4 strips * 8 J * 32 KB = 32 MB

    dist_kernel<<<dim3(8, 4, Bc), 256, 0, stream>>>(X, Y, Dsk);
    scan_kernel<<<Bc, 256, 0, stream>>>(Dsk, xl, yl, out);
}

// Round 7
// 223.481 us; speedup vs baseline: 1.8846x; 1.0138x over previous
//
#include <hip/hip_runtime.h>
#include <hip/hip_fp16.h>
#include <cstddef>

#define Bc   32
#define Nc   512
#define Mc   512
#define DFc  64
#define BIGC 1.0e10f
#define LOG2E_F 1.4426950408889634f
#define LN2_F   0.6931471805599453f
#define SQRT_LOG2E_F 1.2011224087864498f

typedef unsigned int uint32;

// lane l gets lane l-1's src; lane 0 gets `oldv`  (DPP wave_shr:1)
__device__ __forceinline__ float dpp_shr1(float oldv, float src) {
    return __int_as_float(__builtin_amdgcn_update_dpp(
        __float_as_int(oldv), __float_as_int(src), 0x138, 0xf, 0xf, false));
}
// shift with don't-care lane0 (single v_mov_b32_dpp)
__device__ __forceinline__ float dpp_shr1_nc(float src) {
    return __int_as_float(__builtin_amdgcn_mov_dpp(
        __float_as_int(src), 0x138, 0xf, 0xf, false));
}

// Scaled-domain softmin with bit-trick exp2/log2 (no quarter-rate trans ops).
__device__ __forceinline__ float softmin3f(float a, float b, float c) {
    float mn = fminf(fminf(a, b), c);
    float mx = fmaxf(fmaxf(a, b), c);
    float md = __builtin_amdgcn_fmed3f(a, b, c);
    float t1 = mn - mx;                       // <= 0
    float t2 = mn - md;                       // <= 0
    uint32 b1 = (uint32)fmaxf(fmaf(t1, 8388608.0f, 1065353216.0f), 0.0f);
    uint32 b2 = (uint32)fmaxf(fmaf(t2, 8388608.0f, 1065353216.0f), 0.0f);
    float E = 1.0f + (__int_as_float(b1) + __int_as_float(b2));
    float lg = fmaf((float)__float_as_uint(E), 1.1920929e-7f, -127.0f);
    return mn - lg;
}

// ---------------------------------------------------------------------------
// Kernel 1 (rewritten): distances in SCALED (x LOG2E) fp16 via packed-fp16
// math. Inputs pre-scaled by sqrt(LOG2E) at staging so acc == D*LOG2E free.
// LDS: fp16 slabs with granule-8 rotation (conflict-light), then a
// pair-interleaved P[pair][col] half2 buffer whose dwords ARE the Dsk words.
//   Dsk uint4 [tile*1024 + gi*64 + l], comp e: half2(D[2l][c], D[2l+1][c])
//   * LOG2E, c = 4*gi+e-l clamped to [0,63] (garbage never consumed).
// ---------------------------------------------------------------------------
__global__ __launch_bounds__(256) void dist_kernel(
    const float* __restrict__ X, const float* __restrict__ Y,
    uint32* __restrict__ Dsk)
{
    __shared__ __align__(16) unsigned char SMEM[25600];
    unsigned short* XsH = (unsigned short*)SMEM;            // [128][64] rotated
    unsigned short* YsH = (unsigned short*)(SMEM + 16384);  // [64][64] rotated
    uint32* P = (uint32*)SMEM;                              // [64][68] (aliases)

    const int b  = blockIdx.z;
    const int strip = blockIdx.y;          // 128-row band
    const int J  = blockIdx.x;             // 64-col band
    const int tid = threadIdx.x;

    const float* Xg = X + ((size_t)b * Nc + strip * 128) * DFc;
    const float* Yg = Y + ((size_t)b * Mc + J * 128 / 2) * DFc;  // J*64 rows of Y

    // ---- stage X: 128x64 fp32 -> fp16 (x sqrt(LOG2E)), row-rotated ----
#pragma unroll
    for (int it = 0; it < 8; ++it) {
        int e4 = it * 256 + tid;
        int n = e4 >> 4, k4 = (e4 & 15) * 4;
        float4 v = ((const float4*)Xg)[e4];
        __half2 h01 = __floats2half2_rn(v.x * SQRT_LOG2E_F, v.y * SQRT_LOG2E_F);
        __half2 h23 = __floats2half2_rn(v.z * SQRT_LOG2E_F, v.w * SQRT_LOG2E_F);
        int ho = (k4 + 8 * ((n >> 3) & 7)) & 63;
        uint2 u; u.x = *(uint32*)&h01; u.y = *(uint32*)&h23;
        *(uint2*)&XsH[n * 64 + ho] = u;
    }
    // ---- stage Y: 64x64 ----
#pragma unroll
    for (int it = 0; it < 4; ++it) {
        int e4 = it * 256 + tid;
        int m = e4 >> 4, k4 = (e4 & 15) * 4;
        float4 v = ((const float4*)Yg)[e4];
        __half2 h01 = __floats2half2_rn(v.x * SQRT_LOG2E_F, v.y * SQRT_LOG2E_F);
        __half2 h23 = __floats2half2_rn(v.z * SQRT_LOG2E_F, v.w * SQRT_LOG2E_F);
        int ho = (k4 + 8 * ((m >> 2) & 7)) & 63;
        uint2 u; u.x = *(uint32*)&h01; u.y = *(uint32*)&h23;
        *(uint2*)&YsH[m * 64 + ho] = u;
    }
    __syncthreads();

    const int tx = tid & 15;   // 4 cols: 4tx..4tx+3
    const int ty = tid >> 4;   // 8 rows: 8ty..8ty+7

    __half2 acc[8][4];
#pragma unroll
    for (int a = 0; a < 8; ++a)
#pragma unroll
        for (int c = 0; c < 4; ++c) acc[a][c] = __floats2half2_rn(0.f, 0.f);

    const int xrot = 8 * (ty & 7);
    const int yrot = 8 * (tx & 7);

#pragma unroll 2
    for (int k8 = 0; k8 < 8; ++k8) {
        uint4 xv[8], yvv[4];
#pragma unroll
        for (int a = 0; a < 8; ++a) {
            int r = 8 * ty + a;
            xv[a] = *(const uint4*)&XsH[r * 64 + ((k8 * 8 + xrot) & 63)];
        }
#pragma unroll
        for (int c = 0; c < 4; ++c) {
            int m = 4 * tx + c;
            yvv[c] = *(const uint4*)&YsH[m * 64 + ((k8 * 8 + yrot) & 63)];
        }
#pragma unroll
        for (int a = 0; a < 8; ++a) {
            const uint32 xa[4] = {xv[a].x, xv[a].y, xv[a].z, xv[a].w};
#pragma unroll
            for (int c = 0; c < 4; ++c) {
                const uint32 ya[4] = {yvv[c].x, yvv[c].y, yvv[c].z, yvv[c].w};
#pragma unroll
                for (int t = 0; t < 4; ++t) {
                    __half2 xd = *(const __half2*)&xa[t];
                    __half2 yd = *(const __half2*)&ya[t];
                    __half2 d = __hsub2(xd, yd);
                    acc[a][c] = __hfma2(d, d, acc[a][c]);
                }
            }
        }
    }
    __syncthreads();   // all XsH/YsH reads done; P may overwrite

    // ---- fold even/odd-k partials, pack pair-interleaved P ----
#pragma unroll
    for (int u = 0; u < 4; ++u) {
        uint32 dw[4];
#pragma unroll
        for (int c = 0; c < 4; ++c) {
            float2 fa = __half22float2(acc[2 * u][c]);
            float2 fb = __half22float2(acc[2 * u + 1][c]);
            __half2 hh = __floats2half2_rn(fa.x + fa.y, fb.x + fb.y);
            dw[c] = *(uint32*)&hh;
        }
        int p = 4 * ty + u;
        uint4 v4; v4.x = dw[0]; v4.y = dw[1]; v4.z = dw[2]; v4.w = dw[3];
        *(uint4*)&P[p * 68 + 4 * tx] = v4;
    }
    __syncthreads();

    // ---- skew gather (stride-1 banks, 2-way free) + coalesced b128 store ----
    const int l = tid & 63;
    const int q = tid >> 6;
    uint4* outt = (uint4*)Dsk + (((size_t)b * 4 + strip) * 8 + J) * 2048;
    const uint32* Pl = P + l * 68;
#pragma unroll
    for (int g = 0; g < 8; ++g) {
        int gi = q + 4 * g;
        uint32 u[4];
#pragma unroll
        for (int e = 0; e < 4; ++e) {
            int c = min(max(4 * gi + e - l, 0), 63);
            u[e] = Pl[c];
        }
        uint4 v4; v4.x = u[0]; v4.y = u[1]; v4.z = u[2]; v4.w = u[3];
        outt[gi * 64 + l] = v4;
    }
}

// ---------------------------------------------------------------------------
// Kernel 2 (unchanged from r6): tile-systolic scan, 2 rows/lane, 1 batch per
// block (4 waves, 1/SIMD), bit-trick softmin, dead-tile skip.
// ---------------------------------------------------------------------------
__global__ __launch_bounds__(256) void scan_kernel(
    const uint32* __restrict__ Dsk,
    const int* __restrict__ X_len, const int* __restrict__ Y_len,
    float* __restrict__ out)
{
    __shared__ __align__(16) float Frow[4][516];
    __shared__ float dumpArr[80];

    const int tid = threadIdx.x;
    const int l  = tid & 63;
    const int wl = __builtin_amdgcn_readfirstlane(tid >> 6);  // strip 0..3
    const int bb = blockIdx.x;

    const int xl = X_len[bb], yl = Y_len[bb];
    const int wxl = (xl - 1) >> 7;            // capture strip
    const int iw  = (xl - 1) & 127;
    const int lcap = iw >> 1;                 // capture lane
    const int useB = iw & 1;                  // row parity within lane
    const int Jcap = (yl - 1) >> 6;           // capture tile
    const int scapBase = (yl - (Jcap << 6)) + lcap;   // in [1,127]
    const int kmax = wxl + Jcap;              // <= 10

    const bool is63 = (l == 63);

    if (l == 0) Frow[wl][0] = BIGC;   // col-0 border, read as f0 at J=0
    __syncthreads();

    float curA = BIGC, curB = BIGC;
    float diagA = (wl == 0 && l == 0) ? 0.0f : BIGC;
    float capv = 0.0f;

    for (int k = 0; k <= kmax; ++k) {
        int J = k - wl;
        if (wl <= wxl && 0 <= J && J <= Jcap) {
            const int j0 = J << 6;
            float Fv, f0;
            if (wl > 0) {
                Fv = Frow[wl - 1][j0 + 1 + l];   // frontier cols j0+1..j0+64
                f0 = Frow[wl - 1][j0];           // frontier col j0 (diag seed)
            } else {
                Fv = BIGC;
                f0 = (J == 0) ? 0.0f : BIGC;     // R[0][0]=0, else border
            }
            diagA = (l == 0) ? f0 : diagA;

            const uint4* tp = (const uint4*)Dsk +
                ((((size_t)bb * 4 + wl) * 8) + J) * 2048 + l;
            const int scap = (wl == wxl && J == Jcap) ? scapBase : -1000;
            float* wb = is63 ? (&Frow[wl][0] + j0 + 1) : dumpArr;

            uint4 dreg[4];
            dreg[0] = tp[0];   dreg[1] = tp[64];
            dreg[2] = tp[128]; dreg[3] = tp[192];

            // ---- phase 1: gi 0..15, s = 1..64: lane0 inject, no stores ----
#pragma unroll 1
            for (int m = 0; m < 4; ++m) {
#pragma unroll
                for (int q = 0; q < 4; ++q) {
                    const int gi = m * 4 + q;            // gi & 3 == q
                    uint4 dc = dreg[q];
                    dreg[q] = tp[(gi + 4) * 64];         // 4-deep slot reuse
                    const uint32 du[4] = {dc.x, dc.y, dc.z, dc.w};
#pragma unroll
                    for (int e = 0; e < 4; ++e) {
                        const int s = 4 * gi + e + 1;    // 1..64
                        float2 d2 = __half22float2(*(const __half2*)&du[e]);
                        float fs = __int_as_float(__builtin_amdgcn_readlane(
                            __float_as_int(Fv), s - 1));
                        float upA = dpp_shr1(fs, curB);
                        float valA = softmin3f(diagA, upA, curA) + d2.x;
                        float valB = softmin3f(curA, valA, curB) + d2.y;
                        float vsel = useB ? valB : valA;
                        capv = (s == scap) ? vsel : capv;
                        bool act = (l <= s - 1);
                        curA = act ? valA : curA;
                        curB = act ? valB : curB;
                        diagA = upA;
                    }
                }
            }
            // s=64 frontier publish: lane63's curB -> col j0+1
            wb[0] = curB;

            // ---- phase 2: gi 16..27, s = 65..112: no inject, store each ----
#pragma unroll 1
            for (int m = 4; m < 7; ++m) {
#pragma unroll
                for (int q = 0; q < 4; ++q) {
                    const int gi = m * 4 + q;
                    uint4 dc = dreg[q];
                    dreg[q] = tp[(gi + 4) * 64];
                    const uint32 du[4] = {dc.x, dc.y, dc.z, dc.w};
#pragma unroll
                    for (int e = 0; e < 4; ++e) {
                        const int s = 4 * gi + e + 1;    // 65..112
                        float2 d2 = __half22float2(*(const __half2*)&du[e]);
                        float upA = dpp_shr1_nc(curB);   // lane0 dead
                        float valA = softmin3f(diagA, upA, curA) + d2.x;
                        float valB = softmin3f(curA, valA, curB) + d2.y;
                        float vsel = useB ? valB : valA;
                        capv = (s == scap) ? vsel : capv;
                        bool act = (l >= s - 64);
                        curA = act ? valA : curA;
                        curB = act ? valB : curB;
                        diagA = upA;
                        wb[s - 64] = valB;               // imm-offset ds_write
                    }
                }
            }
            // ---- peel: gi 28..31, s = 113..128 (no prefetch; skip s=128) ----
#pragma unroll
            for (int q = 0; q < 4; ++q) {
                const int gi = 28 + q;
                uint4 dc = dreg[q];
                const uint32 du[4] = {dc.x, dc.y, dc.z, dc.w};
#pragma unroll
                for (int e = 0; e < 4; ++e) {
                    const int s = 4 * gi + e + 1;        // 113..128
                    float2 d2 = __half22float2(*(const __half2*)&du[e]);
                    float upA = dpp_shr1_nc(curB);
                    float valA = softmin3f(diagA, upA, curA) + d2.x;
                    float valB = softmin3f(curA, valA, curB) + d2.y;
                    float vsel = useB ? valB : valA;
                    capv = (s == scap) ? vsel : capv;
                    bool act = (l >= s - 64);
                    curA = act ? valA : curA;
                    curB = act ? valB : curB;
                    diagA = upA;
                    if (s != 128) wb[s - 64] = valB;
                }
            }
        }
        __syncthreads();
    }

    if (wl == wxl) {
        float o = __int_as_float(
            __builtin_amdgcn_readlane(__float_as_int(capv), lcap));
        if (l == 0) out[bb] = o * LN2_F;
    }
}

extern "C" void kernel_launch(void* const* d_in, const int* in_sizes, int n_in,
                              void* d_out, int out_size, void* d_ws, size_t ws_size,
                              hipStream_t stream)
{
    const float* X  = (const float*)d_in[0];
    const float* Y  = (const float*)d_in[1];
    const int*   xl = (const int*)d_in[2];
    const int*   yl = (const int*)d_in[3];
    float* out = (float*)d_out;
    uint32* Dsk = (uint32*)d_ws;   // 32 b * 4 strips * 8 J * 32 KB = 32 MB

    dist_kernel<<<dim3(8, 4, Bc), 256, 0, stream>>>(X, Y, Dsk);
    scan_kernel<<<Bc, 256, 0, stream>>>(Dsk, xl, yl, out);
}